// Round 1
// baseline (9656.111 us; speedup 1.0000x reference)
//
#include <hip/hip_runtime.h>
#include <hip/hip_bf16.h>

// SAE forward: sae_out, feature_acts(dense, top-k sparse), fvu
// Inputs: x[N,Din] f32, W_enc[Din,Dsae] f32, b_enc[Dsae] f32,
//         W_dec[Dsae,Din] f32, b_dec[Din] f32, k (int, =32)
// Output layout (flat f32): sae_out[N*Din] | feature_acts[N*Dsae] | fvu[1]

#define MAXK 32

// ---------------------------------------------------------------- encode GEMM
// feats = relu((x - b_dec) @ W_enc + b_enc), written dense to d_out region.
#define BM 128
#define BN 128
#define BK 16

__global__ __launch_bounds__(256)
void encode_gemm(const float* __restrict__ x, const float* __restrict__ W,
                 const float* __restrict__ b_enc, const float* __restrict__ b_dec,
                 float* __restrict__ feats, int Ntok, int Din, int Dsae) {
  __shared__ float As[BK][BM + 4];   // +4 pad: staging writes & frag reads conflict-free
  __shared__ float Bs[BK][BN];
  const int tid = threadIdx.x;
  const int bm0 = blockIdx.y * BM;
  const int bn0 = blockIdx.x * BN;
  const int arow = tid >> 1;          // 0..127
  const int ak0  = (tid & 1) * 8;     // 0 or 8
  const int bq   = tid >> 5;          // 0..7
  const int bn4  = (tid & 31) * 4;    // 0..124
  const int tx = tid & 15, ty = tid >> 4;

  float acc[8][8];
#pragma unroll
  for (int i = 0; i < 8; ++i)
#pragma unroll
    for (int j = 0; j < 8; ++j) acc[i][j] = 0.f;

  for (int k0 = 0; k0 < Din; k0 += BK) {
    __syncthreads();
    // ---- stage A (as [k][m], minus b_dec)
    const float* ap = x + (size_t)(bm0 + arow) * Din + (k0 + ak0);
    float4 av0 = *(const float4*)ap;
    float4 av1 = *(const float4*)(ap + 4);
    const float* bdp = b_dec + k0 + ak0;
    As[ak0 + 0][arow] = av0.x - bdp[0];
    As[ak0 + 1][arow] = av0.y - bdp[1];
    As[ak0 + 2][arow] = av0.z - bdp[2];
    As[ak0 + 3][arow] = av0.w - bdp[3];
    As[ak0 + 4][arow] = av1.x - bdp[4];
    As[ak0 + 5][arow] = av1.y - bdp[5];
    As[ak0 + 6][arow] = av1.z - bdp[6];
    As[ak0 + 7][arow] = av1.w - bdp[7];
    // ---- stage B (natural [k][n])
    const float* bp = W + (size_t)(k0 + bq) * Dsae + (bn0 + bn4);
    float4 bv0 = *(const float4*)bp;
    float4 bv1 = *(const float4*)(bp + (size_t)8 * Dsae);
    *(float4*)&Bs[bq][bn4]     = bv0;
    *(float4*)&Bs[bq + 8][bn4] = bv1;
    __syncthreads();
    // ---- compute
#pragma unroll
    for (int kk = 0; kk < BK; ++kk) {
      float a[8], b[8];
      *(float4*)&a[0] = *(const float4*)&As[kk][ty * 8];
      *(float4*)&a[4] = *(const float4*)&As[kk][ty * 8 + 4];
      *(float4*)&b[0] = *(const float4*)&Bs[kk][tx * 8];
      *(float4*)&b[4] = *(const float4*)&Bs[kk][tx * 8 + 4];
#pragma unroll
      for (int i = 0; i < 8; ++i)
#pragma unroll
        for (int j = 0; j < 8; ++j)
          acc[i][j] = fmaf(a[i], b[j], acc[i][j]);
    }
  }
  // ---- epilogue: + b_enc, relu, store
#pragma unroll
  for (int i = 0; i < 8; ++i) {
    const int row = bm0 + ty * 8 + i;
    float* out = feats + (size_t)row * Dsae + (bn0 + tx * 8);
    const float* be = b_enc + (bn0 + tx * 8);
    float4 o0, o1;
    o0.x = fmaxf(acc[i][0] + be[0], 0.f);
    o0.y = fmaxf(acc[i][1] + be[1], 0.f);
    o0.z = fmaxf(acc[i][2] + be[2], 0.f);
    o0.w = fmaxf(acc[i][3] + be[3], 0.f);
    o1.x = fmaxf(acc[i][4] + be[4], 0.f);
    o1.y = fmaxf(acc[i][5] + be[5], 0.f);
    o1.z = fmaxf(acc[i][6] + be[6], 0.f);
    o1.w = fmaxf(acc[i][7] + be[7], 0.f);
    *(float4*)out       = o0;
    *(float4*)(out + 4) = o1;
  }
}

// ---------------------------------------------------------------- top-k
// One block per row. Row -> LDS, k iterations of block-wide argmax
// (min-index tie-break, matching lax.top_k stability), then rewrite the
// row as zeros + scattered top-k values. (val,idx) saved to ws for decode.
__global__ __launch_bounds__(256)
void topk_kernel(float* __restrict__ feats, float* __restrict__ topv,
                 int* __restrict__ topi, const int* __restrict__ kptr, int Dsae) {
  const int tid = threadIdx.x;
  const int row = blockIdx.x;
  float* frow = feats + (size_t)row * Dsae;
  __shared__ float buf[16384];
  __shared__ unsigned long long wred[4];
  __shared__ unsigned long long bestk;
  __shared__ float svals[MAXK];
  __shared__ int   sidx[MAXK];

  const int nvec = Dsae / 4;
  for (int i = tid; i < nvec; i += 256) ((float4*)buf)[i] = ((const float4*)frow)[i];
  __syncthreads();

  int k = *kptr; if (k > MAXK) k = MAXK;
  const int chunk = Dsae / 256;       // 64
  const int c0 = tid * chunk;

  // local max over own chunk (ascending scan keeps smallest index on ties)
  float lv = buf[c0]; int li = c0;
  for (int i = 1; i < chunk; ++i) {
    float v = buf[c0 + i];
    if (v > lv) { lv = v; li = c0 + i; }
  }

  const int wid = tid >> 6, lane = tid & 63;
  for (int it = 0; it < k; ++it) {
    // all values are >=0 (post-relu), so float bits are order-preserving
    unsigned long long key =
        ((unsigned long long)__float_as_uint(lv) << 32) |
        (unsigned long long)(0xFFFFFFFFu - (unsigned)li);
#pragma unroll
    for (int s = 32; s; s >>= 1) {
      unsigned long long o = __shfl_xor(key, s);
      if (o > key) key = o;
    }
    if (lane == 0) wred[wid] = key;
    __syncthreads();
    if (tid == 0) {
      unsigned long long b = wred[0];
      for (int w = 1; w < 4; ++w) if (wred[w] > b) b = wred[w];
      bestk = b;
      svals[it] = __uint_as_float((unsigned)(b >> 32));
      sidx[it]  = (int)(0xFFFFFFFFu - (unsigned)b);
    }
    __syncthreads();
    const int bi = (int)(0xFFFFFFFFu - (unsigned)bestk);
    if (bi >= c0 && bi < c0 + chunk) {   // owner: clear & rescan
      buf[bi] = -1.0f;
      lv = buf[c0]; li = c0;
      for (int i = 1; i < chunk; ++i) {
        float v = buf[c0 + i];
        if (v > lv) { lv = v; li = c0 + i; }
      }
    }
    __syncthreads();
  }

  // rewrite row: zeros everywhere, then scatter top-k
  float4 z = {0.f, 0.f, 0.f, 0.f};
  for (int i = tid; i < nvec; i += 256) ((float4*)frow)[i] = z;
  __syncthreads();
  if (tid < k) {
    frow[sidx[tid]] = svals[tid];
    topv[(size_t)row * MAXK + tid] = svals[tid];
    topi[(size_t)row * MAXK + tid] = sidx[tid];
  }
}

// ---------------------------------------------------------------- decode
// sae_out[row,:] = b_dec + sum_j v_j * W_dec[idx_j,:]
__global__ __launch_bounds__(256)
void decode_kernel(const float* __restrict__ topv, const int* __restrict__ topi,
                   const float* __restrict__ W_dec, const float* __restrict__ b_dec,
                   float* __restrict__ sae_out, const int* __restrict__ kptr, int Din) {
  const int tid = threadIdx.x, row = blockIdx.x;
  __shared__ float sv[MAXK];
  __shared__ int   si[MAXK];
  int k = *kptr; if (k > MAXK) k = MAXK;
  if (tid < k) {
    sv[tid] = topv[(size_t)row * MAXK + tid];
    si[tid] = topi[(size_t)row * MAXK + tid];
  }
  __syncthreads();
  // Din = 2048 = 256 threads * 8 floats
  float4 acc0 = ((const float4*)b_dec)[tid];
  float4 acc1 = ((const float4*)b_dec)[tid + 256];
  for (int j = 0; j < k; ++j) {
    const float v = sv[j];
    const float4* wr = (const float4*)(W_dec + (size_t)si[j] * Din);
    float4 w0 = wr[tid];
    float4 w1 = wr[tid + 256];
    acc0.x = fmaf(v, w0.x, acc0.x);
    acc0.y = fmaf(v, w0.y, acc0.y);
    acc0.z = fmaf(v, w0.z, acc0.z);
    acc0.w = fmaf(v, w0.w, acc0.w);
    acc1.x = fmaf(v, w1.x, acc1.x);
    acc1.y = fmaf(v, w1.y, acc1.y);
    acc1.z = fmaf(v, w1.z, acc1.z);
    acc1.w = fmaf(v, w1.w, acc1.w);
  }
  float4* out = (float4*)(sae_out + (size_t)row * Din);
  out[tid]       = acc0;
  out[tid + 256] = acc1;
}

// ---------------------------------------------------------------- fvu
// per-column: sum_n (sae_out-x)^2, sum x, sum x^2 -> ratio; then mean.
__global__ __launch_bounds__(256)
void colstats_kernel(const float* __restrict__ x, const float* __restrict__ sae_out,
                     float* __restrict__ ratios, int Ntok, int Din) {
  const int tid = threadIdx.x;
  const int c  = blockIdx.x * 64 + (tid & 63);
  const int r0 = tid >> 6;             // 0..3
  float sd2 = 0.f, sx = 0.f, sx2 = 0.f;
  for (int n = r0; n < Ntok; n += 4) {
    size_t off = (size_t)n * Din + c;
    float xv = x[off];
    float so = sae_out[off];
    float d = so - xv;
    sd2 = fmaf(d, d, sd2);
    sx += xv;
    sx2 = fmaf(xv, xv, sx2);
  }
  __shared__ float s0[4][64], s1[4][64], s2[4][64];
  s0[r0][tid & 63] = sd2;
  s1[r0][tid & 63] = sx;
  s2[r0][tid & 63] = sx2;
  __syncthreads();
  if (r0 == 0) {
    const int cc = tid & 63;
    float a  = s0[0][cc] + s0[1][cc] + s0[2][cc] + s0[3][cc];
    float b  = s1[0][cc] + s1[1][cc] + s1[2][cc] + s1[3][cc];
    float c2 = s2[0][cc] + s2[1][cc] + s2[2][cc] + s2[3][cc];
    float var = c2 - b * b / (float)Ntok;   // sum (x - mean)^2
    ratios[c] = a / var;
  }
}

__global__ __launch_bounds__(256)
void fvu_finalize(const float* __restrict__ ratios, float* __restrict__ fvu_out, int Din) {
  const int tid = threadIdx.x;
  float s = 0.f;
  for (int i = tid; i < Din; i += 256) s += ratios[i];
#pragma unroll
  for (int off = 32; off; off >>= 1) s += __shfl_xor(s, off);
  __shared__ float ws[4];
  if ((tid & 63) == 0) ws[tid >> 6] = s;
  __syncthreads();
  if (tid == 0) fvu_out[0] = (ws[0] + ws[1] + ws[2] + ws[3]) / (float)Din;
}

// ---------------------------------------------------------------- launch
extern "C" void kernel_launch(void* const* d_in, const int* in_sizes, int n_in,
                              void* d_out, int out_size, void* d_ws, size_t ws_size,
                              hipStream_t stream) {
  const float* x     = (const float*)d_in[0];
  const float* W_enc = (const float*)d_in[1];
  const float* b_enc = (const float*)d_in[2];
  const float* W_dec = (const float*)d_in[3];
  const float* b_dec = (const float*)d_in[4];
  const int*   kptr  = (const int*)d_in[5];

  const int Din  = in_sizes[4];            // 2048
  const int Dsae = in_sizes[2];            // 16384
  const int Ntok = in_sizes[0] / Din;      // 8192

  float* sae_out = (float*)d_out;
  float* feats   = sae_out + (size_t)Ntok * Din;
  float* fvu_out = feats + (size_t)Ntok * Dsae;

  float* topv   = (float*)d_ws;
  int*   topi   = (int*)(topv + (size_t)Ntok * MAXK);
  float* ratios = (float*)(topi + (size_t)Ntok * MAXK);

  dim3 g1(Dsae / BN, Ntok / BM);
  encode_gemm<<<g1, 256, 0, stream>>>(x, W_enc, b_enc, b_dec, feats, Ntok, Din, Dsae);
  topk_kernel<<<Ntok, 256, 0, stream>>>(feats, topv, topi, kptr, Dsae);
  decode_kernel<<<Ntok, 256, 0, stream>>>(topv, topi, W_dec, b_dec, sae_out, kptr, Din);
  colstats_kernel<<<Din / 64, 256, 0, stream>>>(x, sae_out, ratios, Ntok, Din);
  fvu_finalize<<<1, 256, 0, stream>>>(ratios, fvu_out, Din);
}